// Round 1
// baseline (779.373 us; speedup 1.0000x reference)
//
#include <hip/hip_runtime.h>

// StyleGAN3 filtered_lrelu, fused single kernel.
// x: (1024, 128, 128) fp32 (N*C folded), f: 12 taps fp32, out: (1024, 128, 128) fp32.
//
// Math (derived from reference jax convs):
//   fk[t] = f[11-t]  (conv flip)
//   up-stage (per axis, gain 2):  v[i] = 2 * sum_{s=0..5} fk[2s + (1-(i&1))] * x[(i>>1)-5+s]
//     (polyphase of: pad 11 lo / 11 hi around zero-inserted signal, 12-tap xcorr; i in [0,266))
//   mid: leaky relu slope 0.01
//   down-stage (per axis): out[o] = sum_{t=0..11} fk[t] * z[2o+t]   (stride 2, no pad)

#define HH 128
#define WW 128
#define NCH 1024
#define TAPS 12
#define TH 16
#define TW 16
#define IR 42   // intermediate rows per tile  (2*TH + 10)
#define IC 42   // intermediate cols per tile
#define XR 26   // input halo rows (TH + 10)
#define XC 26   // input halo cols

__global__ __launch_bounds__(256) void flrelu_fused(
    const float* __restrict__ x, const float* __restrict__ f, float* __restrict__ out)
{
    __shared__ float xs[XR][XC + 1];
    __shared__ float vs[IR][XC + 1];
    __shared__ float zs[IR][IC + 1];
    __shared__ float ws[TH][IC + 1];

    const int tid = threadIdx.x;
    const int nc  = blockIdx.y;
    const int ho0 = (blockIdx.x >> 3) * TH;   // 8x8 tiles per 128x128 image
    const int wo0 = (blockIdx.x & 7) * TW;

    // reversed filter taps in registers (uniform loads, fully unrolled consumers)
    float fk[TAPS];
#pragma unroll
    for (int t = 0; t < TAPS; ++t) fk[t] = f[TAPS - 1 - t];

    const float* xin = x + (size_t)nc * HH * WW;

    // ---- load input halo: rows [ho0-5, ho0+20], cols [wo0-5, wo0+20], zero OOB ----
    for (int e = tid; e < XR * XC; e += 256) {
        int r = e / XC, c = e % XC;
        int gr = ho0 - 5 + r, gc = wo0 - 5 + c;
        float val = 0.f;
        if (gr >= 0 && gr < HH && gc >= 0 && gc < WW) val = xin[gr * WW + gc];
        xs[r][c] = val;
    }
    __syncthreads();

    // ---- vertical up-filter: vs[i][c], i in [0,42), c in [0,26) ----
    for (int e = tid; e < IR * XC; e += 256) {
        int i = e / XC, c = e % XC;
        int base = i >> 1;
        int tap0 = 1 - (i & 1);           // even i -> taps 1,3,..,11 ; odd i -> 0,2,..,10
        float acc = 0.f;
#pragma unroll
        for (int s = 0; s < 6; ++s) acc += fk[2 * s + tap0] * xs[base + s][c];
        vs[i][c] = 2.0f * acc;
    }
    __syncthreads();

    // ---- horizontal up-filter + leaky relu: zs[i][j], 42x42 ----
    for (int e = tid; e < IR * IC; e += 256) {
        int i = e / IC, j = e % IC;
        int base = j >> 1;
        int tap0 = 1 - (j & 1);
        float acc = 0.f;
#pragma unroll
        for (int s = 0; s < 6; ++s) acc += fk[2 * s + tap0] * vs[i][base + s];
        acc *= 2.0f;
        zs[i][j] = acc >= 0.f ? acc : 0.01f * acc;
    }
    __syncthreads();

    // ---- vertical down-filter: ws[ho][j], 16x42 ----
    for (int e = tid; e < TH * IC; e += 256) {
        int ho = e / IC, j = e % IC;
        float acc = 0.f;
#pragma unroll
        for (int t = 0; t < TAPS; ++t) acc += fk[t] * zs[2 * ho + t][j];
        ws[ho][j] = acc;
    }
    __syncthreads();

    // ---- horizontal down-filter + store: 16x16 outputs, one per thread ----
    {
        int ho = tid >> 4, wo = tid & 15;
        float acc = 0.f;
#pragma unroll
        for (int t = 0; t < TAPS; ++t) acc += fk[t] * ws[ho][2 * wo + t];
        out[((size_t)nc * HH + (ho0 + ho)) * WW + (wo0 + wo)] = acc;
    }
}

extern "C" void kernel_launch(void* const* d_in, const int* in_sizes, int n_in,
                              void* d_out, int out_size, void* d_ws, size_t ws_size,
                              hipStream_t stream) {
    const float* x = (const float*)d_in[0];
    const float* f = (const float*)d_in[1];
    float* out = (float*)d_out;
    dim3 grid(64, NCH);
    flrelu_fused<<<grid, 256, 0, stream>>>(x, f, out);
}

// Round 2
// 147.506 us; speedup vs baseline: 5.2837x; 5.2837x over previous
//
#include <hip/hip_runtime.h>

// StyleGAN3 filtered_lrelu, fused, register/LDS-blocked.
// x: (1024,128,128) fp32, f: 12 taps, out: (1024,128,128) fp32.
//
// Math (identical to the verified R0 kernel):
//   fk[t] = f[11-t]
//   up (per axis, gain 2): for out idx i: base=i>>1, tap0=1-(i&1):
//       v[i] = 2 * sum_{s<6} fk[2s+tap0] * src[base+s]
//   leaky relu slope 0.01 between the two up and two down passes
//   down (per axis): out[o] = sum_{t<12} fk[t] * z[2o+t]
//
// Tile: 32x32 outputs/block, 256 threads.
//   xs  42x42 halo (stride 48)     -> A: vertical-up pairs   -> vs 74x42 (stride 48)
//   B: horizontal-up pairs + lrelu -> zs 74x74 (stride 76; cols 74,75 garbage-ok)
//   C: vertical-down (float4)      -> ws 32x74 (stride 76, reuses xs region)
//   D: horizontal-down (float4 reads) -> global float2 stores
// LDS = (2432 + 3552 + 5624) floats = 46432 B -> 3 blocks/CU.

#define TAPS 12

__global__ __launch_bounds__(256) void flrelu_fused(
    const float* __restrict__ x, const float* __restrict__ f, float* __restrict__ out)
{
    __shared__ float smem[11608];
    float* xs = smem;            // [42][48]
    float* ws = smem;            // [32][76]  (after xs is dead)
    float* vs = smem + 2432;     // [74][48]
    float* zs = smem + 5984;     // [74][76]

    const int tid = threadIdx.x;
    const int nc  = blockIdx.y;
    const int ho0 = (blockIdx.x >> 2) * 32;
    const int wo0 = (blockIdx.x & 3) * 32;
    const int tx = tid & 15, ty = tid >> 4;

    float fk[TAPS];
#pragma unroll
    for (int t = 0; t < TAPS; ++t) fk[t] = f[TAPS - 1 - t];

    const float* xin = x + (size_t)nc * (128 * 128);

    // ---- load 42x42 input halo (rows ho0-5.., cols wo0-5..), zero OOB ----
#pragma unroll
    for (int k = 0; k < 7; ++k) {
        int e = tid + 256 * k;
        if (e < 42 * 42) {
            int r = e / 42, c = e - r * 42;
            int gr = ho0 - 5 + r, gc = wo0 - 5 + c;
            float v = 0.f;
            if ((unsigned)gr < 128u && (unsigned)gc < 128u) v = xin[gr * 128 + gc];
            xs[r * 48 + c] = v;
        }
    }
    __syncthreads();

    // ---- A: vertical up. pair rows (2m,2m+1), pair cols (2cc,2cc+1) ----
#pragma unroll
    for (int k = 0; k < 3; ++k) {
        int m = ty + 16 * k;
        if (m < 37) {
#pragma unroll
            for (int cq = 0; cq < 2; ++cq) {
                int cc = tx + 16 * cq;
                if (cc < 21) {
                    float2 v[6];
#pragma unroll
                    for (int s = 0; s < 6; ++s)
                        v[s] = *(const float2*)(xs + (m + s) * 48 + 2 * cc);
                    float ex = 0.f, ey = 0.f, ox = 0.f, oy = 0.f;
#pragma unroll
                    for (int s = 0; s < 6; ++s) {
                        ex += fk[2 * s + 1] * v[s].x;  ey += fk[2 * s + 1] * v[s].y;
                        ox += fk[2 * s]     * v[s].x;  oy += fk[2 * s]     * v[s].y;
                    }
                    *(float2*)(vs + (2 * m) * 48 + 2 * cc)     = make_float2(2.f * ex, 2.f * ey);
                    *(float2*)(vs + (2 * m + 1) * 48 + 2 * cc) = make_float2(2.f * ox, 2.f * oy);
                }
            }
        }
    }
    __syncthreads();

    // ---- B: horizontal up + lrelu. each task: 4 consecutive cols j=4p..4p+3 ----
#pragma unroll
    for (int k = 0; k < 5; ++k) {
        int i = ty + 16 * k;
        if (i < 74) {
#pragma unroll
            for (int pq = 0; pq < 2; ++pq) {
                int p = tx + 16 * pq;
                if (p < 19) {
                    const float* vp = vs + i * 48 + 2 * p;
                    float2 a = *(const float2*)(vp);
                    float2 b = *(const float2*)(vp + 2);
                    float2 c = *(const float2*)(vp + 4);
                    float v6 = vp[6];
                    float v0 = a.x, v1 = a.y, v2 = b.x, v3 = b.y, v4 = c.x, v5 = c.y;
                    float z0 = fk[1]*v0 + fk[3]*v1 + fk[5]*v2 + fk[7]*v3 + fk[9]*v4 + fk[11]*v5;
                    float z1 = fk[0]*v0 + fk[2]*v1 + fk[4]*v2 + fk[6]*v3 + fk[8]*v4 + fk[10]*v5;
                    float z2 = fk[1]*v1 + fk[3]*v2 + fk[5]*v3 + fk[7]*v4 + fk[9]*v5 + fk[11]*v6;
                    float z3 = fk[0]*v1 + fk[2]*v2 + fk[4]*v3 + fk[6]*v4 + fk[8]*v5 + fk[10]*v6;
                    z0 *= 2.f; z1 *= 2.f; z2 *= 2.f; z3 *= 2.f;
                    z0 = z0 >= 0.f ? z0 : 0.01f * z0;
                    z1 = z1 >= 0.f ? z1 : 0.01f * z1;
                    z2 = z2 >= 0.f ? z2 : 0.01f * z2;
                    z3 = z3 >= 0.f ? z3 : 0.01f * z3;
                    *(float4*)(zs + i * 76 + 4 * p) = make_float4(z0, z1, z2, z3);
                }
            }
        }
    }
    __syncthreads();

    // ---- C: vertical down. float4 column-quads ----
#pragma unroll
    for (int k = 0; k < 2; ++k) {
        int ho = ty + 16 * k;
#pragma unroll
        for (int pq = 0; pq < 2; ++pq) {
            int p = tx + 16 * pq;
            if (p < 19) {
                const float* zp = zs + (2 * ho) * 76 + 4 * p;
                float ax = 0.f, ay = 0.f, az = 0.f, aw = 0.f;
#pragma unroll
                for (int u = 0; u < 12; ++u) {
                    float4 zr = *(const float4*)(zp + u * 76);
                    ax += fk[u] * zr.x; ay += fk[u] * zr.y;
                    az += fk[u] * zr.z; aw += fk[u] * zr.w;
                }
                *(float4*)(ws + ho * 76 + 4 * p) = make_float4(ax, ay, az, aw);
            }
        }
    }
    __syncthreads();

    // ---- D: horizontal down, 2 outputs/task, float2 store ----
#pragma unroll
    for (int k = 0; k < 2; ++k) {
        int ho = ty + 16 * k;
        const float* wp = ws + ho * 76 + 4 * tx;
        float4 r0 = *(const float4*)(wp);
        float4 r1 = *(const float4*)(wp + 4);
        float4 r2 = *(const float4*)(wp + 8);
        float4 r3 = *(const float4*)(wp + 12);
        float w[16] = { r0.x, r0.y, r0.z, r0.w, r1.x, r1.y, r1.z, r1.w,
                        r2.x, r2.y, r2.z, r2.w, r3.x, r3.y, r3.z, r3.w };
        float o0 = 0.f, o1 = 0.f;
#pragma unroll
        for (int t = 0; t < TAPS; ++t) {
            o0 += fk[t] * w[t];
            o1 += fk[t] * w[t + 2];
        }
        *(float2*)(out + ((size_t)nc * 128 + (ho0 + ho)) * 128 + wo0 + 2 * tx)
            = make_float2(o0, o1);
    }
}

extern "C" void kernel_launch(void* const* d_in, const int* in_sizes, int n_in,
                              void* d_out, int out_size, void* d_ws, size_t ws_size,
                              hipStream_t stream) {
    const float* x = (const float*)d_in[0];
    const float* f = (const float*)d_in[1];
    float* out = (float*)d_out;
    dim3 grid(16, 1024);
    flrelu_fused<<<grid, 256, 0, stream>>>(x, f, out);
}